// Round 3
// baseline (8473.713 us; speedup 1.0000x reference)
//
#include <hip/hip_runtime.h>
#include <math.h>
#include <stdint.h>

#define NN 50000
#define FIN 128
#define HD 64
#define CD 32
#define EE 1600000
#define CSTV 1e-5f

typedef unsigned short u16;
typedef unsigned int u32;

static __device__ __forceinline__ float b2f(u16 u){
  union { float f; u32 i; } v; v.i = ((u32)u) << 16; return v.f;
}
static __device__ __forceinline__ u16 f2b(float f){
  union { float f; u32 u; } v; v.f = f;
  u32 u = v.u;
  u32 r = (u + 0x7fffu + ((u >> 16) & 1u)) >> 16;
  return (u16)r;
}
// dual-dtype input load: isf=1 -> fp32 array, isf=0 -> bf16(u16) array
static __device__ __forceinline__ float ldin(const void* p, size_t i, int isf){
  return isf ? ((const float*)p)[i] : b2f(((const u16*)p)[i]);
}

// ---------------- dtype detect ----------------
// bf16 W_in values are all |v| <= ~0.089. If the buffer is fp32, half the u16s
// are random mantissa halves -> as bf16, |v|>1 (or NaN) with p~0.5 each.
__global__ void k_detect(const u16* __restrict__ w, int* __restrict__ flag){
  __shared__ int bad;
  if (threadIdx.x == 0) bad = 0;
  __syncthreads();
  for (int i = threadIdx.x; i < 2048; i += 256){
    float v = b2f(w[i]);
    if (!(fabsf(v) <= 1.0f)) bad = 1;   // catches NaN too
  }
  __syncthreads();
  if (threadIdx.x == 0) flag[0] = bad;  // 1 = fp32 inputs, 0 = bf16
}

// ---------------- CSR build ----------------

__global__ void k_zero(int* cnt, float* teleM, float* teleK){
  int i = blockIdx.x * 256 + threadIdx.x;
  if (i < NN) cnt[i] = 0;
  if (i < HD * CD) teleM[i] = 0.f;
  if (i < HD) teleK[i] = 0.f;
}

__global__ void k_hist(const int* __restrict__ colp, int* __restrict__ cnt){
  int e = blockIdx.x * 256 + threadIdx.x;
  if (e < EE) atomicAdd(&cnt[colp[e]], 1);
}

__global__ void k_scan(const int* __restrict__ cnt, int* __restrict__ ptr,
                       int* __restrict__ fill, float* __restrict__ dinv){
  __shared__ int buf[1024];
  __shared__ int carry;
  int t = threadIdx.x;
  if (t == 0) carry = 0;
  __syncthreads();
  for (int base = 0; base < NN; base += 1024){
    int i = base + t;
    int v = (i < NN) ? cnt[i] : 0;
    buf[t] = v;
    __syncthreads();
    for (int s = 1; s < 1024; s <<= 1){
      int add = (t >= s) ? buf[t - s] : 0;
      __syncthreads();
      buf[t] += add;
      __syncthreads();
    }
    int incl = buf[t];
    int excl = incl - v;
    if (i < NN){
      int p = carry + excl;
      ptr[i] = p; fill[i] = p;
      dinv[i] = (v > 0) ? 1.0f / (float)v : 0.0f;
    }
    __syncthreads();
    if (t == 1023) carry += incl;
    __syncthreads();
  }
  if (t == 0) ptr[NN] = carry;
}

__global__ void k_scatter(const int* __restrict__ rowp, const int* __restrict__ colp,
                          int* __restrict__ fill, int* __restrict__ srcv){
  int e = blockIdx.x * 256 + threadIdx.x;
  if (e < EE){
    int c = colp[e];
    int p = atomicAdd(&fill[c], 1);
    srcv[p] = rowp[e];
  }
}

// ---------------- featurizer ----------------

__global__ __launch_bounds__(256) void k_x(const void* __restrict__ feat, const void* __restrict__ Win,
                                           const void* __restrict__ bin, const int* __restrict__ fl,
                                           float* __restrict__ x){
  int isf = fl[0];
  __shared__ float Ws[FIN * HD];
  __shared__ float fs[4 * FIN];
  __shared__ float bs[HD];
  int t = threadIdx.x;
  for (int idx = t; idx < FIN * HD; idx += 256) Ws[idx] = ldin(Win, idx, isf);
  if (t < HD) bs[t] = ldin(bin, t, isf);
  int n0 = blockIdx.x * 4;
  for (int idx = t; idx < 4 * FIN; idx += 256){
    int nl = idx >> 7, k = idx & 127; int n = n0 + nl;
    fs[idx] = (n < NN) ? ldin(feat, (size_t)n * FIN + k, isf) : 0.f;
  }
  __syncthreads();
  int nl = t >> 6, o = t & 63; int n = n0 + nl;
  if (n < NN){
    float acc = bs[o];
    #pragma unroll 8
    for (int k = 0; k < FIN; ++k) acc += fs[nl * FIN + k] * Ws[k * HD + o];
    x[(size_t)n * HD + o] = fmaxf(acc, 0.f);
  }
}

__global__ __launch_bounds__(256) void k_qkv(const float* __restrict__ x,
    const void* __restrict__ WQ, const void* __restrict__ bQ,
    const void* __restrict__ WK, const void* __restrict__ bK,
    const void* __restrict__ WV, const void* __restrict__ bV,
    const void* __restrict__ hopwise, const int* __restrict__ fl,
    float* __restrict__ Q, float* __restrict__ Kf, float* __restrict__ V,
    float* __restrict__ hid){
  int isf = fl[0];
  __shared__ float WQs[HD * HD], WKs[HD * HD], WVs[HD * CD];
  __shared__ float bqs[HD], bks[HD], bvs[CD];
  __shared__ float xs[4 * HD];
  int t = threadIdx.x;
  for (int idx = t; idx < HD * HD; idx += 256){ WQs[idx] = ldin(WQ, idx, isf); WKs[idx] = ldin(WK, idx, isf); }
  for (int idx = t; idx < HD * CD; idx += 256) WVs[idx] = ldin(WV, idx, isf);
  if (t < HD){ bqs[t] = ldin(bQ, t, isf); bks[t] = ldin(bK, t, isf); }
  if (t < CD) bvs[t] = ldin(bV, t, isf);
  int n0 = blockIdx.x * 4;
  for (int idx = t; idx < 4 * HD; idx += 256){
    int nl = idx >> 6; int n = n0 + nl;
    xs[idx] = (n < NN) ? x[(size_t)n * HD + (idx & 63)] : 0.f;
  }
  __syncthreads();
  int nl = t >> 6, o = t & 63; int n = n0 + nl;
  float hw0 = ldin(hopwise, 0, isf);
  float q = bqs[o], kf = bks[o];
  #pragma unroll 8
  for (int k = 0; k < HD; ++k){
    float xv = xs[nl * HD + k];
    q  += xv * WQs[k * HD + o];
    kf += xv * WKs[k * HD + o];
  }
  q  = (q  > 0.f) ? 1.f + q  : expf(q);
  kf = (kf > 0.f) ? 1.f + kf : expf(kf);
  if (n < NN){ Q[(size_t)n * HD + o] = q; Kf[(size_t)n * HD + o] = kf; }
  if (o < CD && n < NN){
    float v = bvs[o];
    #pragma unroll 8
    for (int k = 0; k < HD; ++k) v += xs[nl * HD + k] * WVs[k * CD + o];
    V[(size_t)n * CD + o] = v;
    hid[(size_t)n * CD + o] = hw0 * v;
  }
}

// ---------------- teleport sums ----------------

__global__ __launch_bounds__(256) void k_tele(const float* __restrict__ Kf, const float* __restrict__ V,
                                              float* __restrict__ teleM, float* __restrict__ teleK){
  __shared__ float accM[HD * CD];
  __shared__ float accKs[HD];
  __shared__ float KfL[HD];
  __shared__ float VL[CD];
  int t = threadIdx.x;
  for (int idx = t; idx < HD * CD; idx += 256) accM[idx] = 0.f;
  if (t < HD) accKs[t] = 0.f;
  __syncthreads();
  for (int n = blockIdx.x; n < NN; n += gridDim.x){
    if (t < HD) KfL[t] = Kf[(size_t)n * HD + t];
    else if (t < HD + CD) VL[t - HD] = V[(size_t)n * CD + (t - HD)];
    __syncthreads();
    for (int idx = t; idx < HD * CD; idx += 256){
      int h = idx >> 5, c = idx & 31;
      accM[idx] += KfL[h] * VL[c];
    }
    if (t < HD) accKs[t] += KfL[t];
    __syncthreads();
  }
  for (int idx = t; idx < HD * CD; idx += 256) atomicAdd(&teleM[idx], accM[idx]);
  if (t < HD) atomicAdd(&teleK[t], accKs[t]);
}

// ---------------- Kf propagation (per hop) + inv-denominator ----------------

__global__ __launch_bounds__(64) void k_kprop(const float* __restrict__ Kfin, const float* __restrict__ Qb,
    const int* __restrict__ ptr, const int* __restrict__ srcv, const float* __restrict__ dinv,
    float* __restrict__ Kfout, float* __restrict__ invC){
  int i = blockIdx.x, t = threadIdx.x;
  int e0 = ptr[i], e1 = ptr[i + 1];
  float acc = 0.f;
  for (int e = e0; e < e1; ++e){
    int r = srcv[e];
    acc += dinv[r] * Kfin[(size_t)r * HD + t];
  }
  Kfout[(size_t)i * HD + t] = acc;
  float ck = Qb[(size_t)i * HD + t] * acc;
  #pragma unroll
  for (int off = 32; off >= 1; off >>= 1) ck += __shfl_down(ck, off, 64);
  if (t == 0) invC[i] = 1.f / (ck + CSTV);
}

// ---------------- build M0 column chunk ----------------

template<bool F32>
__global__ __launch_bounds__(256) void k_m0(const float* __restrict__ Kf0, const float* __restrict__ V,
                                            void* __restrict__ M, int c0, int C){
  int idx = blockIdx.x * 256 + threadIdx.x;
  int per_row = HD * C;
  if (idx >= NN * per_row) return;
  int n = idx / per_row;
  int rem = idx - n * per_row;
  int h = rem / C;
  int c = rem - h * C;
  float val = Kf0[(size_t)n * HD + h] * V[(size_t)n * CD + c0 + c];
  if (F32) ((float*)M)[idx] = val;
  else ((u16*)M)[idx] = f2b(val);
}

// ---------------- chunked hop: gather-propagate + fused readout ----------------
// M chunk layout per node: element e = h*C + c (h in [0,HD), c in [0,C)).
// Block = one target node; thread t owns elements [4t, 4t+4).

template<int C, bool F32>
__global__ __launch_bounds__(HD * C / 4)
void k_hopc(const void* __restrict__ Min, const float* __restrict__ Qb,
            const int* __restrict__ ptr, const int* __restrict__ srcv,
            const float* __restrict__ dinv, const float* __restrict__ invC,
            const void* __restrict__ hopw, const int* __restrict__ fl, int hopidx,
            void* __restrict__ Mout, float* __restrict__ hid, int c0, int last){
  constexpr int T = HD * C / 4;              // threads = float4s per row
  constexpr int G = (C >= 4) ? C / 4 : 1;    // surviving reduction groups
  __shared__ float Qs[HD];
  __shared__ float4 red[T];
  int i = blockIdx.x, t = threadIdx.x;
  int isf = fl[0];
  for (int j = t; j < HD; j += T) Qs[j] = Qb[(size_t)i * HD + j];
  int e0 = ptr[i], e1 = ptr[i + 1];
  float4 a = make_float4(0.f, 0.f, 0.f, 0.f);
  if (F32){
    const float4* base = (const float4*)Min;
    for (int e = e0; e < e1; ++e){
      int r = srcv[e];
      float w = dinv[r];
      float4 x4 = base[(size_t)r * T + t];
      a.x += w * x4.x; a.y += w * x4.y; a.z += w * x4.z; a.w += w * x4.w;
    }
  } else {
    const ushort4* base = (const ushort4*)Min;
    for (int e = e0; e < e1; ++e){
      int r = srcv[e];
      float w = dinv[r];
      ushort4 x4 = base[(size_t)r * T + t];
      a.x += w * b2f(x4.x); a.y += w * b2f(x4.y);
      a.z += w * b2f(x4.z); a.w += w * b2f(x4.w);
    }
  }
  __syncthreads();
  int eb = 4 * t;
  float4 p;
  p.x = Qs[(eb + 0) / C] * a.x;
  p.y = Qs[(eb + 1) / C] * a.y;
  p.z = Qs[(eb + 2) / C] * a.z;
  p.w = Qs[(eb + 3) / C] * a.w;
  red[t] = p;
  __syncthreads();
  #pragma unroll
  for (int s = T / 2; s >= G; s >>= 1){
    if (t < s){
      float4 o4 = red[t + s];
      red[t].x += o4.x; red[t].y += o4.y; red[t].z += o4.z; red[t].w += o4.w;
    }
    __syncthreads();
  }
  float coef = ldin(hopw, hopidx, isf) * invC[i];
  if (C >= 4){
    if (t < G){
      float4 Hv = red[t];
      float* hp = hid + (size_t)i * CD + c0 + 4 * t;
      hp[0] += coef * Hv.x; hp[1] += coef * Hv.y;
      hp[2] += coef * Hv.z; hp[3] += coef * Hv.w;
    }
  } else if (C == 2){
    if (t == 0){
      float4 Hv = red[0];
      hid[(size_t)i * CD + c0]     += coef * (Hv.x + Hv.z);
      hid[(size_t)i * CD + c0 + 1] += coef * (Hv.y + Hv.w);
    }
  } else {
    if (t == 0){
      float4 Hv = red[0];
      hid[(size_t)i * CD + c0] += coef * (Hv.x + Hv.y + Hv.z + Hv.w);
    }
  }
  if (!last){
    if (F32){
      ((float4*)Mout)[(size_t)i * T + t] = a;
    } else {
      ushort4 ov;
      ov.x = f2b(a.x); ov.y = f2b(a.y); ov.z = f2b(a.z); ov.w = f2b(a.w);
      ((ushort4*)Mout)[(size_t)i * T + t] = ov;
    }
  }
}

// ---------------- teleport branch + output ----------------

__global__ __launch_bounds__(256) void k_final(const float* __restrict__ hid, const float* __restrict__ Qb,
    const float* __restrict__ teleM, const float* __restrict__ teleK, const void* __restrict__ tel,
    const int* __restrict__ fl, void* __restrict__ out){
  int isf = fl[0];
  __shared__ float tM[HD * CD];
  __shared__ float tK[HD];
  int t = threadIdx.x;
  for (int idx = t; idx < HD * CD; idx += 256) tM[idx] = teleM[idx];
  if (t < HD) tK[t] = teleK[t];
  __syncthreads();
  int nl = t >> 5, c = t & 31;
  int n = blockIdx.x * 8 + nl;
  if (n < NN){
    const float* q = Qb + (size_t)n * HD;
    float dH = 0.f, dK = 0.f;
    #pragma unroll 8
    for (int h = 0; h < HD; ++h){
      float qv = q[h];
      dH += qv * tM[h * CD + c];
      dK += qv * tK[h];
    }
    float invn = 1.f / (float)NN;
    float tH = (dH * invn) / (dK * invn + CSTV);
    float val = hid[(size_t)n * CD + c] + ldin(tel, 0, isf) * tH;
    if (isf) ((float*)out)[(size_t)n * CD + c] = val;
    else ((u16*)out)[(size_t)n * CD + c] = f2b(val);
  }
}

// ---------------- launch ----------------

extern "C" void kernel_launch(void* const* d_in, const int* in_sizes, int n_in,
                              void* d_out, int out_size, void* d_ws, size_t ws_size,
                              hipStream_t stream){
  const void* feat = d_in[0];
  const void* Win  = d_in[1];
  const void* bin  = d_in[2];
  const void* WQ   = d_in[3];
  const void* bQ   = d_in[4];
  const void* WK   = d_in[5];
  const void* bK   = d_in[6];
  const void* WV   = d_in[7];
  const void* bV   = d_in[8];
  const void* hop  = d_in[9];
  const void* tel  = d_in[10];
  const int* ei    = (const int*)d_in[11];
  const int* rowp  = ei;
  const int* colp  = ei + EE;

  char* w = (char*)d_ws;
  size_t off = 0;
  auto alloc = [&](size_t bytes) -> char* {
    char* p = w + off;
    off += (bytes + 255) & ~((size_t)255);
    return p;
  };
  float* Q    = (float*)alloc((size_t)NN * HD * 4);
  float* Kf0  = (float*)alloc((size_t)NN * HD * 4);
  float* KfA  = (float*)alloc((size_t)NN * HD * 4);
  float* KfB  = (float*)alloc((size_t)NN * HD * 4);
  float* V    = (float*)alloc((size_t)NN * CD * 4);
  float* hid  = (float*)alloc((size_t)NN * CD * 4);
  float* invC = (float*)alloc((size_t)4 * NN * 4);
  float* dinv = (float*)alloc((size_t)NN * 4);
  int*   cnt  = (int*)alloc((size_t)NN * 4);
  int*   ptr  = (int*)alloc((size_t)(NN + 1) * 4);
  int*   fill = (int*)alloc((size_t)NN * 4);
  int*   srcv = (int*)alloc((size_t)EE * 4);
  float* teleM= (float*)alloc((size_t)HD * CD * 4);
  float* teleK= (float*)alloc((size_t)HD * 4);
  int*   flag = (int*)alloc(256);

  // tier select: never exceed ws_size
  size_t fixed = off;
  auto pad = [](size_t x){ return (x + 255) & ~((size_t)255); };
  auto fits = [&](size_t mb){ return fixed + 2 * pad(mb) <= ws_size; };
  int C; bool f32m;
  if      (fits((size_t)NN * HD * 4 * 4)){ C = 4; f32m = true;  }
  else if (fits((size_t)NN * HD * 2 * 4)){ C = 2; f32m = true;  }
  else if (fits((size_t)NN * HD * 4 * 2)){ C = 4; f32m = false; }
  else if (fits((size_t)NN * HD * 2 * 2)){ C = 2; f32m = false; }
  else                                   { C = 1; f32m = false; }
  size_t mbytes = pad((size_t)NN * HD * C * (f32m ? 4 : 2));
  char* mreg = alloc(2 * mbytes);
  void* Ma = (void*)mreg;
  void* Mb = (void*)(mreg + mbytes);
  float* x = (float*)mreg;  // x (12.8 MB) aliases chunk region (>= 12.8 MB in all tiers); dead before k_m0

  k_detect<<<1, 256, 0, stream>>>((const u16*)Win, flag);
  k_zero<<<(NN + 255) / 256, 256, 0, stream>>>(cnt, teleM, teleK);
  k_hist<<<(EE + 255) / 256, 256, 0, stream>>>(colp, cnt);
  k_scan<<<1, 1024, 0, stream>>>(cnt, ptr, fill, dinv);
  k_scatter<<<(EE + 255) / 256, 256, 0, stream>>>(rowp, colp, fill, srcv);
  k_x<<<(NN + 3) / 4, 256, 0, stream>>>(feat, Win, bin, flag, x);
  k_qkv<<<(NN + 3) / 4, 256, 0, stream>>>(x, WQ, bQ, WK, bK, WV, bV, hop, flag, Q, Kf0, V, hid);
  k_tele<<<256, 256, 0, stream>>>(Kf0, V, teleM, teleK);

  k_kprop<<<NN, 64, 0, stream>>>(Kf0, Q, ptr, srcv, dinv, KfA, invC + 0 * NN);
  k_kprop<<<NN, 64, 0, stream>>>(KfA, Q, ptr, srcv, dinv, KfB, invC + 1 * NN);
  k_kprop<<<NN, 64, 0, stream>>>(KfB, Q, ptr, srcv, dinv, KfA, invC + 2 * NN);
  k_kprop<<<NN, 64, 0, stream>>>(KfA, Q, ptr, srcv, dinv, KfB, invC + 3 * NN);

  int nchunks = CD / C;
  for (int ch = 0; ch < nchunks; ++ch){
    int c0 = ch * C;
    int total = NN * HD * C;
    if (f32m) k_m0<true ><<<(total + 255) / 256, 256, 0, stream>>>(Kf0, V, Ma, c0, C);
    else      k_m0<false><<<(total + 255) / 256, 256, 0, stream>>>(Kf0, V, Ma, c0, C);
    for (int hp = 1; hp <= 4; ++hp){
      void* Mi = (hp & 1) ? Ma : Mb;
      void* Mo = (hp & 1) ? Mb : Ma;
      int last = (hp == 4);
      const float* ic = invC + (hp - 1) * NN;
      if (f32m){
        if (C == 4) k_hopc<4, true ><<<NN, HD * 4 / 4, 0, stream>>>(Mi, Q, ptr, srcv, dinv, ic, hop, flag, hp, Mo, hid, c0, last);
        else        k_hopc<2, true ><<<NN, HD * 2 / 4, 0, stream>>>(Mi, Q, ptr, srcv, dinv, ic, hop, flag, hp, Mo, hid, c0, last);
      } else {
        if (C == 4)      k_hopc<4, false><<<NN, HD * 4 / 4, 0, stream>>>(Mi, Q, ptr, srcv, dinv, ic, hop, flag, hp, Mo, hid, c0, last);
        else if (C == 2) k_hopc<2, false><<<NN, HD * 2 / 4, 0, stream>>>(Mi, Q, ptr, srcv, dinv, ic, hop, flag, hp, Mo, hid, c0, last);
        else             k_hopc<1, false><<<NN, HD * 1 / 4, 0, stream>>>(Mi, Q, ptr, srcv, dinv, ic, hop, flag, hp, Mo, hid, c0, last);
      }
    }
  }
  k_final<<<(NN + 7) / 8, 256, 0, stream>>>(hid, Q, teleM, teleK, tel, flag, d_out);
}

// Round 4
// 4081.472 us; speedup vs baseline: 2.0761x; 2.0761x over previous
//
#include <hip/hip_runtime.h>
#include <math.h>
#include <stdint.h>

#define NN 50000
#define FIN 128
#define HD 64
#define CD 32
#define EE 1600000
#define CSTV 1e-5f

typedef unsigned short u16;
typedef unsigned int u32;

static __device__ __forceinline__ float b2f(u16 u){
  union { float f; u32 i; } v; v.i = ((u32)u) << 16; return v.f;
}
static __device__ __forceinline__ u16 f2b(float f){
  union { float f; u32 u; } v; v.f = f;
  u32 u = v.u;
  u32 r = (u + 0x7fffu + ((u >> 16) & 1u)) >> 16;
  return (u16)r;
}
static __device__ __forceinline__ u32 pack2(float a, float b){
  return (u32)f2b(a) | ((u32)f2b(b) << 16);
}
// dual-dtype input load: isf=1 -> fp32 array, isf=0 -> bf16(u16) array
static __device__ __forceinline__ float ldin(const void* p, size_t i, int isf){
  return isf ? ((const float*)p)[i] : b2f(((const u16*)p)[i]);
}

template<int C>
static __device__ __forceinline__ void loadB(const u16* __restrict__ p, float* f){
  if constexpr (C == 8){
    uint4 g = *(const uint4*)p;
    f[0]=b2f((u16)(g.x&0xffff)); f[1]=b2f((u16)(g.x>>16));
    f[2]=b2f((u16)(g.y&0xffff)); f[3]=b2f((u16)(g.y>>16));
    f[4]=b2f((u16)(g.z&0xffff)); f[5]=b2f((u16)(g.z>>16));
    f[6]=b2f((u16)(g.w&0xffff)); f[7]=b2f((u16)(g.w>>16));
  } else if constexpr (C == 4){
    uint2 g = *(const uint2*)p;
    f[0]=b2f((u16)(g.x&0xffff)); f[1]=b2f((u16)(g.x>>16));
    f[2]=b2f((u16)(g.y&0xffff)); f[3]=b2f((u16)(g.y>>16));
  } else {
    u32 g = *(const u32*)p;
    f[0]=b2f((u16)(g&0xffff)); f[1]=b2f((u16)(g>>16));
  }
}
template<int C>
static __device__ __forceinline__ void storeB(u16* __restrict__ p, const float* f){
  if constexpr (C == 8){
    uint4 g; g.x=pack2(f[0],f[1]); g.y=pack2(f[2],f[3]); g.z=pack2(f[4],f[5]); g.w=pack2(f[6],f[7]);
    *(uint4*)p = g;
  } else if constexpr (C == 4){
    uint2 g; g.x=pack2(f[0],f[1]); g.y=pack2(f[2],f[3]);
    *(uint2*)p = g;
  } else {
    *(u32*)p = pack2(f[0], f[1]);
  }
}

// ---------------- dtype detect ----------------
__global__ void k_detect(const u16* __restrict__ w, int* __restrict__ flag){
  __shared__ int bad;
  if (threadIdx.x == 0) bad = 0;
  __syncthreads();
  for (int i = threadIdx.x; i < 2048; i += 256){
    float v = b2f(w[i]);
    if (!(fabsf(v) <= 1.0f)) bad = 1;
  }
  __syncthreads();
  if (threadIdx.x == 0) flag[0] = bad;  // 1 = fp32 inputs, 0 = bf16
}

// ---------------- CSR build ----------------

__global__ void k_zero(int* cnt, float* teleM, float* teleK){
  int i = blockIdx.x * 256 + threadIdx.x;
  if (i < NN) cnt[i] = 0;
  if (i < HD * CD) teleM[i] = 0.f;
  if (i < HD) teleK[i] = 0.f;
}

__global__ void k_hist(const int* __restrict__ colp, int* __restrict__ cnt){
  int e = blockIdx.x * 256 + threadIdx.x;
  if (e < EE) atomicAdd(&cnt[colp[e]], 1);
}

__global__ void k_scan(const int* __restrict__ cnt, int* __restrict__ ptr,
                       int* __restrict__ fill, float* __restrict__ dinv){
  __shared__ int buf[1024];
  __shared__ int carry;
  int t = threadIdx.x;
  if (t == 0) carry = 0;
  __syncthreads();
  for (int base = 0; base < NN; base += 1024){
    int i = base + t;
    int v = (i < NN) ? cnt[i] : 0;
    buf[t] = v;
    __syncthreads();
    for (int s = 1; s < 1024; s <<= 1){
      int add = (t >= s) ? buf[t - s] : 0;
      __syncthreads();
      buf[t] += add;
      __syncthreads();
    }
    int incl = buf[t];
    int excl = incl - v;
    if (i < NN){
      int p = carry + excl;
      ptr[i] = p; fill[i] = p;
      dinv[i] = (v > 0) ? 1.0f / (float)v : 0.0f;
    }
    __syncthreads();
    if (t == 1023) carry += incl;
    __syncthreads();
  }
  if (t == 0) ptr[NN] = carry;
}

__global__ void k_scatter(const int* __restrict__ rowp, const int* __restrict__ colp,
                          const float* __restrict__ dinv, int* __restrict__ fill,
                          int2* __restrict__ ew){
  int e = blockIdx.x * 256 + threadIdx.x;
  if (e < EE){
    int c = colp[e];
    int p = atomicAdd(&fill[c], 1);
    int r = rowp[e];
    int2 v; v.x = r; v.y = __float_as_int(dinv[r]);
    ew[p] = v;
  }
}

// ---------------- featurizer ----------------

__global__ __launch_bounds__(256) void k_x(const void* __restrict__ feat, const void* __restrict__ Win,
                                           const void* __restrict__ bin, const int* __restrict__ fl,
                                           float* __restrict__ x){
  int isf = fl[0];
  __shared__ float Ws[FIN * HD];
  __shared__ float fs[4 * FIN];
  __shared__ float bs[HD];
  int t = threadIdx.x;
  for (int idx = t; idx < FIN * HD; idx += 256) Ws[idx] = ldin(Win, idx, isf);
  if (t < HD) bs[t] = ldin(bin, t, isf);
  int n0 = blockIdx.x * 4;
  for (int idx = t; idx < 4 * FIN; idx += 256){
    int nl = idx >> 7, k = idx & 127; int n = n0 + nl;
    fs[idx] = (n < NN) ? ldin(feat, (size_t)n * FIN + k, isf) : 0.f;
  }
  __syncthreads();
  int nl = t >> 6, o = t & 63; int n = n0 + nl;
  if (n < NN){
    float acc = bs[o];
    #pragma unroll 8
    for (int k = 0; k < FIN; ++k) acc += fs[nl * FIN + k] * Ws[k * HD + o];
    x[(size_t)n * HD + o] = fmaxf(acc, 0.f);
  }
}

__global__ __launch_bounds__(256) void k_qkv(const float* __restrict__ x,
    const void* __restrict__ WQ, const void* __restrict__ bQ,
    const void* __restrict__ WK, const void* __restrict__ bK,
    const void* __restrict__ WV, const void* __restrict__ bV,
    const void* __restrict__ hopwise, const int* __restrict__ fl,
    float* __restrict__ Q, float* __restrict__ Kf, float* __restrict__ V,
    float* __restrict__ hid){
  int isf = fl[0];
  __shared__ float WQs[HD * HD], WKs[HD * HD], WVs[HD * CD];
  __shared__ float bqs[HD], bks[HD], bvs[CD];
  __shared__ float xs[4 * HD];
  int t = threadIdx.x;
  for (int idx = t; idx < HD * HD; idx += 256){ WQs[idx] = ldin(WQ, idx, isf); WKs[idx] = ldin(WK, idx, isf); }
  for (int idx = t; idx < HD * CD; idx += 256) WVs[idx] = ldin(WV, idx, isf);
  if (t < HD){ bqs[t] = ldin(bQ, t, isf); bks[t] = ldin(bK, t, isf); }
  if (t < CD) bvs[t] = ldin(bV, t, isf);
  int n0 = blockIdx.x * 4;
  for (int idx = t; idx < 4 * HD; idx += 256){
    int nl = idx >> 6; int n = n0 + nl;
    xs[idx] = (n < NN) ? x[(size_t)n * HD + (idx & 63)] : 0.f;
  }
  __syncthreads();
  int nl = t >> 6, o = t & 63; int n = n0 + nl;
  float hw0 = ldin(hopwise, 0, isf);
  float q = bqs[o], kf = bks[o];
  #pragma unroll 8
  for (int k = 0; k < HD; ++k){
    float xv = xs[nl * HD + k];
    q  += xv * WQs[k * HD + o];
    kf += xv * WKs[k * HD + o];
  }
  q  = (q  > 0.f) ? 1.f + q  : expf(q);
  kf = (kf > 0.f) ? 1.f + kf : expf(kf);
  if (n < NN){ Q[(size_t)n * HD + o] = q; Kf[(size_t)n * HD + o] = kf; }
  if (o < CD && n < NN){
    float v = bvs[o];
    #pragma unroll 8
    for (int k = 0; k < HD; ++k) v += xs[nl * HD + k] * WVs[k * CD + o];
    V[(size_t)n * CD + o] = v;
    hid[(size_t)n * CD + o] = hw0 * v;
  }
}

// ---------------- teleport sums ----------------

__global__ __launch_bounds__(256) void k_tele(const float* __restrict__ Kf, const float* __restrict__ V,
                                              float* __restrict__ teleM, float* __restrict__ teleK){
  __shared__ float accM[HD * CD];
  __shared__ float accKs[HD];
  __shared__ float KfL[HD];
  __shared__ float VL[CD];
  int t = threadIdx.x;
  for (int idx = t; idx < HD * CD; idx += 256) accM[idx] = 0.f;
  if (t < HD) accKs[t] = 0.f;
  __syncthreads();
  for (int n = blockIdx.x; n < NN; n += gridDim.x){
    if (t < HD) KfL[t] = Kf[(size_t)n * HD + t];
    else if (t < HD + CD) VL[t - HD] = V[(size_t)n * CD + (t - HD)];
    __syncthreads();
    for (int idx = t; idx < HD * CD; idx += 256){
      int h = idx >> 5, c = idx & 31;
      accM[idx] += KfL[h] * VL[c];
    }
    if (t < HD) accKs[t] += KfL[t];
    __syncthreads();
  }
  for (int idx = t; idx < HD * CD; idx += 256) atomicAdd(&teleM[idx], accM[idx]);
  if (t < HD) atomicAdd(&teleK[t], accKs[t]);
}

// ---------------- bf16 packs of Kf0 and V ----------------

__global__ void k_pack(const float* __restrict__ Kf0, const float* __restrict__ V,
                       u16* __restrict__ Kf0b, u16* __restrict__ Vb){
  int i = blockIdx.x * 256 + threadIdx.x;
  if (i < NN * HD) Kf0b[i] = f2b(Kf0[i]);
  if (i < NN * CD) Vb[i] = f2b(V[i]);
}

// ---------------- Kf propagation (per hop) + inv-denominator ----------------

__global__ __launch_bounds__(64) void k_kprop(const float* __restrict__ Kfin, const float* __restrict__ Qb,
    const int* __restrict__ ptr, const int2* __restrict__ ew,
    float* __restrict__ Kfout, float* __restrict__ invC){
  int i = blockIdx.x, t = threadIdx.x;
  int e0 = ptr[i], e1 = ptr[i + 1];
  float acc = 0.f;
  int e = e0;
  for (; e + 1 < e1; e += 2){
    int2 p0 = ew[e], p1 = ew[e + 1];
    acc += __int_as_float(p0.y) * Kfin[(size_t)p0.x * HD + t];
    acc += __int_as_float(p1.y) * Kfin[(size_t)p1.x * HD + t];
  }
  if (e < e1){
    int2 p0 = ew[e];
    acc += __int_as_float(p0.y) * Kfin[(size_t)p0.x * HD + t];
  }
  Kfout[(size_t)i * HD + t] = acc;
  float ck = Qb[(size_t)i * HD + t] * acc;
  #pragma unroll
  for (int off = 32; off >= 1; off >>= 1) ck += __shfl_down(ck, off, 64);
  if (t == 0) invC[i] = 1.f / (ck + CSTV);
}

// ---------------- hop: gather-propagate + fused readout ----------------
// One wave per target node. Lane t owns row h=t, columns [c0, c0+C).
// FIRST: M_in is implicit rank-1 Kf0 (x) V -> per-edge 2B/lane + 2C uniform bytes.

template<int C, bool FIRST>
__global__ __launch_bounds__(64)
void k_hop(const u16* __restrict__ Min, const u16* __restrict__ Kf0b, const u16* __restrict__ Vb,
           const float* __restrict__ Qb, const int2* __restrict__ ew, const int* __restrict__ ptr,
           const float* __restrict__ invC, const void* __restrict__ hopw, const int* __restrict__ fl,
           int hopidx, u16* __restrict__ Mout, float* __restrict__ hid, int c0, int last){
  int i = blockIdx.x, t = threadIdx.x;
  int e0 = ptr[i], e1 = ptr[i + 1];
  float a[C];
  #pragma unroll
  for (int j = 0; j < C; ++j) a[j] = 0.f;
  int e = e0;
  if (FIRST){
    for (; e + 1 < e1; e += 2){
      int2 p0 = ew[e], p1 = ew[e + 1];
      float s0 = __int_as_float(p0.y) * b2f(Kf0b[(size_t)p0.x * HD + t]);
      float s1 = __int_as_float(p1.y) * b2f(Kf0b[(size_t)p1.x * HD + t]);
      float v0[C], v1[C];
      loadB<C>(Vb + (size_t)p0.x * CD + c0, v0);
      loadB<C>(Vb + (size_t)p1.x * CD + c0, v1);
      #pragma unroll
      for (int j = 0; j < C; ++j){ a[j] += s0 * v0[j]; a[j] += s1 * v1[j]; }
    }
    if (e < e1){
      int2 p0 = ew[e];
      float s0 = __int_as_float(p0.y) * b2f(Kf0b[(size_t)p0.x * HD + t]);
      float v0[C];
      loadB<C>(Vb + (size_t)p0.x * CD + c0, v0);
      #pragma unroll
      for (int j = 0; j < C; ++j) a[j] += s0 * v0[j];
    }
  } else {
    for (; e + 1 < e1; e += 2){
      int2 p0 = ew[e], p1 = ew[e + 1];
      float w0 = __int_as_float(p0.y), w1 = __int_as_float(p1.y);
      float m0[C], m1[C];
      loadB<C>(Min + (size_t)p0.x * (HD * C) + t * C, m0);
      loadB<C>(Min + (size_t)p1.x * (HD * C) + t * C, m1);
      #pragma unroll
      for (int j = 0; j < C; ++j){ a[j] += w0 * m0[j]; a[j] += w1 * m1[j]; }
    }
    if (e < e1){
      int2 p0 = ew[e];
      float w0 = __int_as_float(p0.y);
      float m0[C];
      loadB<C>(Min + (size_t)p0.x * (HD * C) + t * C, m0);
      #pragma unroll
      for (int j = 0; j < C; ++j) a[j] += w0 * m0[j];
    }
  }
  // readout: H[c] = sum_h Q[h] * Mnew[h][c]
  float q = Qb[(size_t)i * HD + t];
  float p[C];
  #pragma unroll
  for (int j = 0; j < C; ++j) p[j] = q * a[j];
  #pragma unroll
  for (int off = 32; off >= 1; off >>= 1){
    #pragma unroll
    for (int j = 0; j < C; ++j) p[j] += __shfl_down(p[j], off, 64);
  }
  if (t == 0){
    float coef = ldin(hopw, hopidx, fl[0]) * invC[i];
    float* hp = hid + (size_t)i * CD + c0;
    #pragma unroll
    for (int j = 0; j < C; ++j) hp[j] += coef * p[j];
  }
  if (!last) storeB<C>(Mout + (size_t)i * (HD * C) + t * C, a);
}

// ---------------- teleport branch + output ----------------

__global__ __launch_bounds__(256) void k_final(const float* __restrict__ hid, const float* __restrict__ Qb,
    const float* __restrict__ teleM, const float* __restrict__ teleK, const void* __restrict__ tel,
    const int* __restrict__ fl, void* __restrict__ out){
  int isf = fl[0];
  __shared__ float tM[HD * CD];
  __shared__ float tK[HD];
  int t = threadIdx.x;
  for (int idx = t; idx < HD * CD; idx += 256) tM[idx] = teleM[idx];
  if (t < HD) tK[t] = teleK[t];
  __syncthreads();
  int nl = t >> 5, c = t & 31;
  int n = blockIdx.x * 8 + nl;
  if (n < NN){
    const float* q = Qb + (size_t)n * HD;
    float dH = 0.f, dK = 0.f;
    #pragma unroll 8
    for (int h = 0; h < HD; ++h){
      float qv = q[h];
      dH += qv * tM[h * CD + c];
      dK += qv * tK[h];
    }
    float invn = 1.f / (float)NN;
    float tH = (dH * invn) / (dK * invn + CSTV);
    float val = hid[(size_t)n * CD + c] + ldin(tel, 0, isf) * tH;
    if (isf) ((float*)out)[(size_t)n * CD + c] = val;
    else ((u16*)out)[(size_t)n * CD + c] = f2b(val);
  }
}

// ---------------- launch ----------------

extern "C" void kernel_launch(void* const* d_in, const int* in_sizes, int n_in,
                              void* d_out, int out_size, void* d_ws, size_t ws_size,
                              hipStream_t stream){
  const void* feat = d_in[0];
  const void* Win  = d_in[1];
  const void* bin  = d_in[2];
  const void* WQ   = d_in[3];
  const void* bQ   = d_in[4];
  const void* WK   = d_in[5];
  const void* bK   = d_in[6];
  const void* WV   = d_in[7];
  const void* bV   = d_in[8];
  const void* hop  = d_in[9];
  const void* tel  = d_in[10];
  const int* ei    = (const int*)d_in[11];
  const int* rowp  = ei;
  const int* colp  = ei + EE;

  char* w = (char*)d_ws;
  size_t off = 0;
  auto alloc = [&](size_t bytes) -> char* {
    char* p = w + off;
    off += (bytes + 255) & ~((size_t)255);
    return p;
  };
  float* Q    = (float*)alloc((size_t)NN * HD * 4);
  float* Kf0  = (float*)alloc((size_t)NN * HD * 4);
  float* KfA  = (float*)alloc((size_t)NN * HD * 4);
  float* V    = (float*)alloc((size_t)NN * CD * 4);
  float* hid  = (float*)alloc((size_t)NN * CD * 4);
  float* invC = (float*)alloc((size_t)4 * NN * 4);
  float* dinv = (float*)alloc((size_t)NN * 4);
  int*   cnt  = (int*)alloc((size_t)NN * 4);
  int*   ptr  = (int*)alloc((size_t)(NN + 1) * 4);
  int*   fill = (int*)alloc((size_t)NN * 4);
  int2*  ew   = (int2*)alloc((size_t)EE * 8);
  float* teleM= (float*)alloc((size_t)HD * CD * 4);
  float* teleK= (float*)alloc((size_t)HD * 4);
  int*   flag = (int*)alloc(256);
  u16*   Kf0b = (u16*)alloc((size_t)NN * HD * 2);
  u16*   Vb   = (u16*)alloc((size_t)NN * CD * 2);

  // tier select on chunk width (bf16 M chunks)
  size_t fixed = off;
  auto pad = [](size_t x){ return (x + 255) & ~((size_t)255); };
  auto fits = [&](int C){ return fixed + 2 * pad((size_t)NN * HD * C * 2) <= ws_size; };
  int C = fits(8) ? 8 : (fits(4) ? 4 : 2);
  size_t mbytes = pad((size_t)NN * HD * C * 2);
  char* mreg = alloc(2 * mbytes);
  u16* Ma = (u16*)mreg;
  u16* Mb = (u16*)(mreg + mbytes);
  float* x = (float*)mreg;  // x (12.8 MB) aliases chunk region (>=12.8 MB in all tiers); dead before hops

  k_detect<<<1, 256, 0, stream>>>((const u16*)Win, flag);
  k_zero<<<(NN + 255) / 256, 256, 0, stream>>>(cnt, teleM, teleK);
  k_hist<<<(EE + 255) / 256, 256, 0, stream>>>(colp, cnt);
  k_scan<<<1, 1024, 0, stream>>>(cnt, ptr, fill, dinv);
  k_scatter<<<(EE + 255) / 256, 256, 0, stream>>>(rowp, colp, dinv, fill, ew);
  k_x<<<(NN + 3) / 4, 256, 0, stream>>>(feat, Win, bin, flag, x);
  k_qkv<<<(NN + 3) / 4, 256, 0, stream>>>(x, WQ, bQ, WK, bK, WV, bV, hop, flag, Q, Kf0, V, hid);
  k_tele<<<256, 256, 0, stream>>>(Kf0, V, teleM, teleK);
  k_pack<<<(NN * HD + 255) / 256, 256, 0, stream>>>(Kf0, V, Kf0b, Vb);

  // Kf propagation: ping-pong Kf0 <-> KfA (Kf0 f32 is free after tele+pack)
  k_kprop<<<NN, 64, 0, stream>>>(Kf0, Q, ptr, ew, KfA, invC + 0 * NN);
  k_kprop<<<NN, 64, 0, stream>>>(KfA, Q, ptr, ew, Kf0, invC + 1 * NN);
  k_kprop<<<NN, 64, 0, stream>>>(Kf0, Q, ptr, ew, KfA, invC + 2 * NN);
  k_kprop<<<NN, 64, 0, stream>>>(KfA, Q, ptr, ew, Kf0, invC + 3 * NN);

  int nchunks = CD / C;
  for (int ch = 0; ch < nchunks; ++ch){
    int c0 = ch * C;
    #define HOPARGS(Mi, hp, Mo, last) (const u16*)(Mi), Kf0b, Vb, Q, ew, ptr, invC + ((hp) - 1) * NN, \
                                      hop, flag, (hp), (u16*)(Mo), hid, c0, (last)
    if (C == 8){
      k_hop<8, true ><<<NN, 64, 0, stream>>>(HOPARGS(Ma, 1, Ma, 0));
      k_hop<8, false><<<NN, 64, 0, stream>>>(HOPARGS(Ma, 2, Mb, 0));
      k_hop<8, false><<<NN, 64, 0, stream>>>(HOPARGS(Mb, 3, Ma, 0));
      k_hop<8, false><<<NN, 64, 0, stream>>>(HOPARGS(Ma, 4, Mb, 1));
    } else if (C == 4){
      k_hop<4, true ><<<NN, 64, 0, stream>>>(HOPARGS(Ma, 1, Ma, 0));
      k_hop<4, false><<<NN, 64, 0, stream>>>(HOPARGS(Ma, 2, Mb, 0));
      k_hop<4, false><<<NN, 64, 0, stream>>>(HOPARGS(Mb, 3, Ma, 0));
      k_hop<4, false><<<NN, 64, 0, stream>>>(HOPARGS(Ma, 4, Mb, 1));
    } else {
      k_hop<2, true ><<<NN, 64, 0, stream>>>(HOPARGS(Ma, 1, Ma, 0));
      k_hop<2, false><<<NN, 64, 0, stream>>>(HOPARGS(Ma, 2, Mb, 0));
      k_hop<2, false><<<NN, 64, 0, stream>>>(HOPARGS(Mb, 3, Ma, 0));
      k_hop<2, false><<<NN, 64, 0, stream>>>(HOPARGS(Ma, 4, Mb, 1));
    }
    #undef HOPARGS
  }
  k_final<<<(NN + 7) / 8, 256, 0, stream>>>(hid, Q, teleM, teleK, tel, flag, d_out);
}

// Round 5
// 3673.137 us; speedup vs baseline: 2.3069x; 1.1112x over previous
//
#include <hip/hip_runtime.h>
#include <math.h>
#include <stdint.h>

#define NN 50000
#define FIN 128
#define HD 64
#define CD 32
#define EE 1600000
#define CSTV 1e-5f
#define NB 49  // ceil(NN/1024)

typedef unsigned short u16;
typedef unsigned int u32;
typedef unsigned int uv2 __attribute__((ext_vector_type(2)));
typedef unsigned int uv4 __attribute__((ext_vector_type(4)));

static __device__ __forceinline__ float b2f(u16 u){
  union { float f; u32 i; } v; v.i = ((u32)u) << 16; return v.f;
}
static __device__ __forceinline__ u16 f2b(float f){
  union { float f; u32 u; } v; v.f = f;
  u32 u = v.u;
  u32 r = (u + 0x7fffu + ((u >> 16) & 1u)) >> 16;
  return (u16)r;
}
static __device__ __forceinline__ u32 pack2(float a, float b){
  return (u32)f2b(a) | ((u32)f2b(b) << 16);
}
static __device__ __forceinline__ float ldin(const void* p, size_t i, int isf){
  return isf ? ((const float*)p)[i] : b2f(((const u16*)p)[i]);
}

template<int C>
static __device__ __forceinline__ void loadB(const u16* __restrict__ p, float* f){
  if constexpr (C == 16){
    uint4 g0 = ((const uint4*)p)[0];
    uint4 g1 = ((const uint4*)p)[1];
    f[0]=b2f((u16)(g0.x&0xffff)); f[1]=b2f((u16)(g0.x>>16));
    f[2]=b2f((u16)(g0.y&0xffff)); f[3]=b2f((u16)(g0.y>>16));
    f[4]=b2f((u16)(g0.z&0xffff)); f[5]=b2f((u16)(g0.z>>16));
    f[6]=b2f((u16)(g0.w&0xffff)); f[7]=b2f((u16)(g0.w>>16));
    f[8]=b2f((u16)(g1.x&0xffff)); f[9]=b2f((u16)(g1.x>>16));
    f[10]=b2f((u16)(g1.y&0xffff)); f[11]=b2f((u16)(g1.y>>16));
    f[12]=b2f((u16)(g1.z&0xffff)); f[13]=b2f((u16)(g1.z>>16));
    f[14]=b2f((u16)(g1.w&0xffff)); f[15]=b2f((u16)(g1.w>>16));
  } else if constexpr (C == 8){
    uint4 g = *(const uint4*)p;
    f[0]=b2f((u16)(g.x&0xffff)); f[1]=b2f((u16)(g.x>>16));
    f[2]=b2f((u16)(g.y&0xffff)); f[3]=b2f((u16)(g.y>>16));
    f[4]=b2f((u16)(g.z&0xffff)); f[5]=b2f((u16)(g.z>>16));
    f[6]=b2f((u16)(g.w&0xffff)); f[7]=b2f((u16)(g.w>>16));
  } else if constexpr (C == 4){
    uint2 g = *(const uint2*)p;
    f[0]=b2f((u16)(g.x&0xffff)); f[1]=b2f((u16)(g.x>>16));
    f[2]=b2f((u16)(g.y&0xffff)); f[3]=b2f((u16)(g.y>>16));
  } else {
    u32 g = *(const u32*)p;
    f[0]=b2f((u16)(g&0xffff)); f[1]=b2f((u16)(g>>16));
  }
}
template<int C>
static __device__ __forceinline__ void storeNT(u16* __restrict__ p, const float* f){
  if constexpr (C == 16){
    uv4 g0, g1;
    g0.x=pack2(f[0],f[1]); g0.y=pack2(f[2],f[3]); g0.z=pack2(f[4],f[5]); g0.w=pack2(f[6],f[7]);
    g1.x=pack2(f[8],f[9]); g1.y=pack2(f[10],f[11]); g1.z=pack2(f[12],f[13]); g1.w=pack2(f[14],f[15]);
    __builtin_nontemporal_store(g0, (uv4*)p);
    __builtin_nontemporal_store(g1, (uv4*)p + 1);
  } else if constexpr (C == 8){
    uv4 g; g.x=pack2(f[0],f[1]); g.y=pack2(f[2],f[3]); g.z=pack2(f[4],f[5]); g.w=pack2(f[6],f[7]);
    __builtin_nontemporal_store(g, (uv4*)p);
  } else if constexpr (C == 4){
    uv2 g; g.x=pack2(f[0],f[1]); g.y=pack2(f[2],f[3]);
    __builtin_nontemporal_store(g, (uv2*)p);
  } else {
    __builtin_nontemporal_store(pack2(f[0],f[1]), (u32*)p);
  }
}

// ---------------- dtype detect ----------------
__global__ void k_detect(const u16* __restrict__ w, int* __restrict__ flag){
  __shared__ int bad;
  if (threadIdx.x == 0) bad = 0;
  __syncthreads();
  for (int i = threadIdx.x; i < 2048; i += 256){
    float v = b2f(w[i]);
    if (!(fabsf(v) <= 1.0f)) bad = 1;
  }
  __syncthreads();
  if (threadIdx.x == 0) flag[0] = bad;  // 1 = fp32 inputs, 0 = bf16
}

// ---------------- CSR build ----------------

__global__ void k_zero(int* cnt, float* teleM, float* teleK){
  int i = blockIdx.x * 256 + threadIdx.x;
  if (i < NN) cnt[i] = 0;
  if (i < HD * CD) teleM[i] = 0.f;
  if (i < HD) teleK[i] = 0.f;
}

__global__ void k_hist(const int* __restrict__ colp, int* __restrict__ cnt){
  int e = blockIdx.x * 256 + threadIdx.x;
  if (e < EE) atomicAdd(&cnt[colp[e]], 1);
}

__global__ __launch_bounds__(1024) void k_scanA(const int* __restrict__ cnt,
                                                int* __restrict__ loc, int* __restrict__ bsum){
  __shared__ int wsum[16];
  int t = threadIdx.x; int i = blockIdx.x * 1024 + t;
  int v = (i < NN) ? cnt[i] : 0;
  int x = v;
  int lane = t & 63, wid = t >> 6;
  #pragma unroll
  for (int d = 1; d < 64; d <<= 1){ int n = __shfl_up(x, d, 64); if (lane >= d) x += n; }
  if (lane == 63) wsum[wid] = x;
  __syncthreads();
  if (t < 16){
    int y = wsum[t];
    #pragma unroll
    for (int d = 1; d < 16; d <<= 1){ int n = __shfl_up(y, d, 16); if (t >= d) y += n; }
    wsum[t] = y;
  }
  __syncthreads();
  if (wid > 0) x += wsum[wid - 1];
  if (i < NN) loc[i] = x;
  if (t == 1023) bsum[blockIdx.x] = x;
}

__global__ __launch_bounds__(64) void k_scanB(const int* __restrict__ bsum,
                                              int* __restrict__ boff, int* __restrict__ ptrNN){
  int t = threadIdx.x;
  int v = (t < NB) ? bsum[t] : 0;
  int x = v;
  #pragma unroll
  for (int d = 1; d < 64; d <<= 1){ int n = __shfl_up(x, d, 64); if (t >= d) x += n; }
  if (t < NB) boff[t] = x - v;
  if (t == 63) ptrNN[0] = x;
}

__global__ __launch_bounds__(1024) void k_scanC(const int* __restrict__ cnt, const int* __restrict__ loc,
                                                const int* __restrict__ boff, int* __restrict__ ptr,
                                                int* __restrict__ fill, float* __restrict__ dinv){
  int i = blockIdx.x * 1024 + threadIdx.x;
  if (i < NN){
    int c = cnt[i];
    int p = boff[blockIdx.x] + loc[i] - c;
    ptr[i] = p; fill[i] = p;
    dinv[i] = (c > 0) ? 1.f / (float)c : 0.f;
  }
}

__global__ void k_scatter(const int* __restrict__ rowp, const int* __restrict__ colp,
                          const float* __restrict__ dinv, int* __restrict__ fill,
                          int2* __restrict__ ew){
  int e = blockIdx.x * 256 + threadIdx.x;
  if (e < EE){
    int c = colp[e];
    int p = atomicAdd(&fill[c], 1);
    int r = rowp[e];
    int2 v; v.x = r; v.y = __float_as_int(dinv[r]);
    ew[p] = v;
  }
}

// ---------------- featurizer ----------------

__global__ __launch_bounds__(256) void k_x(const void* __restrict__ feat, const void* __restrict__ Win,
                                           const void* __restrict__ bin, const int* __restrict__ fl,
                                           float* __restrict__ x){
  int isf = fl[0];
  __shared__ float Ws[FIN * HD];
  __shared__ float fs[4 * FIN];
  __shared__ float bs[HD];
  int t = threadIdx.x;
  for (int idx = t; idx < FIN * HD; idx += 256) Ws[idx] = ldin(Win, idx, isf);
  if (t < HD) bs[t] = ldin(bin, t, isf);
  int n0 = blockIdx.x * 4;
  for (int idx = t; idx < 4 * FIN; idx += 256){
    int nl = idx >> 7, k = idx & 127; int n = n0 + nl;
    fs[idx] = (n < NN) ? ldin(feat, (size_t)n * FIN + k, isf) : 0.f;
  }
  __syncthreads();
  int nl = t >> 6, o = t & 63; int n = n0 + nl;
  if (n < NN){
    float acc = bs[o];
    #pragma unroll 8
    for (int k = 0; k < FIN; ++k) acc += fs[nl * FIN + k] * Ws[k * HD + o];
    x[(size_t)n * HD + o] = fmaxf(acc, 0.f);
  }
}

__global__ __launch_bounds__(256) void k_qkv(const float* __restrict__ x,
    const void* __restrict__ WQ, const void* __restrict__ bQ,
    const void* __restrict__ WK, const void* __restrict__ bK,
    const void* __restrict__ WV, const void* __restrict__ bV,
    const void* __restrict__ hopwise, const int* __restrict__ fl,
    float* __restrict__ Q, u16* __restrict__ Kf0b, u16* __restrict__ Vb,
    float* __restrict__ hid){
  int isf = fl[0];
  __shared__ float WQs[HD * HD], WKs[HD * HD], WVs[HD * CD];
  __shared__ float bqs[HD], bks[HD], bvs[CD];
  __shared__ float xs[4 * HD];
  int t = threadIdx.x;
  for (int idx = t; idx < HD * HD; idx += 256){ WQs[idx] = ldin(WQ, idx, isf); WKs[idx] = ldin(WK, idx, isf); }
  for (int idx = t; idx < HD * CD; idx += 256) WVs[idx] = ldin(WV, idx, isf);
  if (t < HD){ bqs[t] = ldin(bQ, t, isf); bks[t] = ldin(bK, t, isf); }
  if (t < CD) bvs[t] = ldin(bV, t, isf);
  int n0 = blockIdx.x * 4;
  for (int idx = t; idx < 4 * HD; idx += 256){
    int nl = idx >> 6; int n = n0 + nl;
    xs[idx] = (n < NN) ? x[(size_t)n * HD + (idx & 63)] : 0.f;
  }
  __syncthreads();
  int nl = t >> 6, o = t & 63; int n = n0 + nl;
  float hw0 = ldin(hopwise, 0, isf);
  float q = bqs[o], kf = bks[o];
  #pragma unroll 8
  for (int k = 0; k < HD; ++k){
    float xv = xs[nl * HD + k];
    q  += xv * WQs[k * HD + o];
    kf += xv * WKs[k * HD + o];
  }
  q  = (q  > 0.f) ? 1.f + q  : expf(q);
  kf = (kf > 0.f) ? 1.f + kf : expf(kf);
  if (n < NN){ Q[(size_t)n * HD + o] = q; Kf0b[(size_t)n * HD + o] = f2b(kf); }
  if (o < CD && n < NN){
    float v = bvs[o];
    #pragma unroll 8
    for (int k = 0; k < HD; ++k) v += xs[nl * HD + k] * WVs[k * CD + o];
    Vb[(size_t)n * CD + o] = f2b(v);
    hid[(size_t)n * CD + o] = hw0 * v;
  }
}

// ---------------- teleport sums ----------------

__global__ __launch_bounds__(256) void k_tele(const u16* __restrict__ Kf0b, const u16* __restrict__ Vb,
                                              float* __restrict__ teleM, float* __restrict__ teleK){
  __shared__ float accM[HD * CD];
  __shared__ float accKs[HD];
  __shared__ float KfL[HD];
  __shared__ float VL[CD];
  int t = threadIdx.x;
  for (int idx = t; idx < HD * CD; idx += 256) accM[idx] = 0.f;
  if (t < HD) accKs[t] = 0.f;
  __syncthreads();
  for (int n = blockIdx.x; n < NN; n += gridDim.x){
    if (t < HD) KfL[t] = b2f(Kf0b[(size_t)n * HD + t]);
    else if (t < HD + CD) VL[t - HD] = b2f(Vb[(size_t)n * CD + (t - HD)]);
    __syncthreads();
    for (int idx = t; idx < HD * CD; idx += 256){
      int h = idx >> 5, c = idx & 31;
      accM[idx] += KfL[h] * VL[c];
    }
    if (t < HD) accKs[t] += KfL[t];
    __syncthreads();
  }
  for (int idx = t; idx < HD * CD; idx += 256) atomicAdd(&teleM[idx], accM[idx]);
  if (t < HD) atomicAdd(&teleK[t], accKs[t]);
}

// ---------------- hop: gather-propagate + fused readout (+optional Kf prop) ----------------
// One wave per target node. Lane t owns row h=t, columns [c0, c0+C).
// FIRST: M_in implicit rank-1 Kf0 (x) V. FUSEK: also propagate Kf + compute invC.

template<int C, bool FIRST, bool FUSEK, bool LAST>
__global__ __launch_bounds__(64)
void k_hop(const u16* __restrict__ Min, const u16* __restrict__ Kf0b, const u16* __restrict__ Vb,
           const u16* __restrict__ KfIn, u16* __restrict__ KfOut,
           const float* __restrict__ Qb, const int2* __restrict__ ew, const int* __restrict__ ptr,
           float* __restrict__ invC, const void* __restrict__ hopw, const int* __restrict__ fl,
           int hopidx, u16* __restrict__ Mout, float* __restrict__ hid, int c0){
  int i = blockIdx.x, t = threadIdx.x;
  int e0 = __builtin_amdgcn_readfirstlane(ptr[i]);
  int e1 = __builtin_amdgcn_readfirstlane(ptr[i + 1]);
  float a[C];
  #pragma unroll
  for (int j = 0; j < C; ++j) a[j] = 0.f;
  float accK = 0.f;
  int e = e0;
  if constexpr (FIRST){
    for (; e + 4 <= e1; e += 4){
      int2 d0 = ew[e], d1 = ew[e+1], d2 = ew[e+2], d3 = ew[e+3];
      float s0 = __int_as_float(d0.y) * b2f(Kf0b[(size_t)d0.x * HD + t]);
      float s1 = __int_as_float(d1.y) * b2f(Kf0b[(size_t)d1.x * HD + t]);
      float s2 = __int_as_float(d2.y) * b2f(Kf0b[(size_t)d2.x * HD + t]);
      float s3 = __int_as_float(d3.y) * b2f(Kf0b[(size_t)d3.x * HD + t]);
      float v0[C], v1[C], v2[C], v3[C];
      loadB<C>(Vb + (size_t)d0.x * CD + c0, v0);
      loadB<C>(Vb + (size_t)d1.x * CD + c0, v1);
      loadB<C>(Vb + (size_t)d2.x * CD + c0, v2);
      loadB<C>(Vb + (size_t)d3.x * CD + c0, v3);
      #pragma unroll
      for (int j = 0; j < C; ++j) a[j] += s0 * v0[j] + s1 * v1[j] + s2 * v2[j] + s3 * v3[j];
      if constexpr (FUSEK) accK += s0 + s1 + s2 + s3;
    }
    for (; e < e1; ++e){
      int2 d0 = ew[e];
      float s0 = __int_as_float(d0.y) * b2f(Kf0b[(size_t)d0.x * HD + t]);
      float v0[C];
      loadB<C>(Vb + (size_t)d0.x * CD + c0, v0);
      #pragma unroll
      for (int j = 0; j < C; ++j) a[j] += s0 * v0[j];
      if constexpr (FUSEK) accK += s0;
    }
  } else {
    for (; e + 4 <= e1; e += 4){
      int2 d0 = ew[e], d1 = ew[e+1], d2 = ew[e+2], d3 = ew[e+3];
      float w0 = __int_as_float(d0.y), w1 = __int_as_float(d1.y);
      float w2 = __int_as_float(d2.y), w3 = __int_as_float(d3.y);
      float m0[C], m1[C], m2[C], m3[C];
      loadB<C>(Min + (size_t)d0.x * (HD * C) + t * C, m0);
      loadB<C>(Min + (size_t)d1.x * (HD * C) + t * C, m1);
      loadB<C>(Min + (size_t)d2.x * (HD * C) + t * C, m2);
      loadB<C>(Min + (size_t)d3.x * (HD * C) + t * C, m3);
      if constexpr (FUSEK){
        accK += w0 * b2f(KfIn[(size_t)d0.x * HD + t]) + w1 * b2f(KfIn[(size_t)d1.x * HD + t])
              + w2 * b2f(KfIn[(size_t)d2.x * HD + t]) + w3 * b2f(KfIn[(size_t)d3.x * HD + t]);
      }
      #pragma unroll
      for (int j = 0; j < C; ++j) a[j] += w0 * m0[j] + w1 * m1[j] + w2 * m2[j] + w3 * m3[j];
    }
    for (; e < e1; ++e){
      int2 d0 = ew[e];
      float w0 = __int_as_float(d0.y);
      float m0[C];
      loadB<C>(Min + (size_t)d0.x * (HD * C) + t * C, m0);
      if constexpr (FUSEK) accK += w0 * b2f(KfIn[(size_t)d0.x * HD + t]);
      #pragma unroll
      for (int j = 0; j < C; ++j) a[j] += w0 * m0[j];
    }
  }
  float q = Qb[(size_t)i * HD + t];
  float ic;
  if constexpr (FUSEK){
    if constexpr (!LAST) KfOut[(size_t)i * HD + t] = f2b(accK);
    float ck = q * accK;
    #pragma unroll
    for (int off = 32; off >= 1; off >>= 1) ck += __shfl_down(ck, off, 64);
    ck = 1.f / (ck + CSTV);          // valid on lane 0
    if (t == 0) invC[i] = ck;
    ic = ck;
  } else {
    ic = invC[i];
  }
  float p[C];
  #pragma unroll
  for (int j = 0; j < C; ++j) p[j] = q * a[j];
  #pragma unroll
  for (int off = 32; off >= 1; off >>= 1){
    #pragma unroll
    for (int j = 0; j < C; ++j) p[j] += __shfl_down(p[j], off, 64);
  }
  if (t == 0){
    float coef = ldin(hopw, hopidx, fl[0]) * ic;
    float* hp = hid + (size_t)i * CD + c0;
    #pragma unroll
    for (int j = 0; j < C; ++j) hp[j] += coef * p[j];
  }
  if constexpr (!LAST) storeNT<C>(Mout + (size_t)i * (HD * C) + t * C, a);
}

// ---------------- teleport branch + output ----------------

__global__ __launch_bounds__(256) void k_final(const float* __restrict__ hid, const float* __restrict__ Qb,
    const float* __restrict__ teleM, const float* __restrict__ teleK, const void* __restrict__ tel,
    const int* __restrict__ fl, void* __restrict__ out){
  int isf = fl[0];
  __shared__ float tM[HD * CD];
  __shared__ float tK[HD];
  int t = threadIdx.x;
  for (int idx = t; idx < HD * CD; idx += 256) tM[idx] = teleM[idx];
  if (t < HD) tK[t] = teleK[t];
  __syncthreads();
  int nl = t >> 5, c = t & 31;
  int n = blockIdx.x * 8 + nl;
  if (n < NN){
    const float* q = Qb + (size_t)n * HD;
    float dH = 0.f, dK = 0.f;
    #pragma unroll 8
    for (int h = 0; h < HD; ++h){
      float qv = q[h];
      dH += qv * tM[h * CD + c];
      dK += qv * tK[h];
    }
    float invn = 1.f / (float)NN;
    float tH = (dH * invn) / (dK * invn + CSTV);
    float val = hid[(size_t)n * CD + c] + ldin(tel, 0, isf) * tH;
    if (isf) ((float*)out)[(size_t)n * CD + c] = val;
    else ((u16*)out)[(size_t)n * CD + c] = f2b(val);
  }
}

// ---------------- host-side hop sequencing ----------------

template<int C>
static void launch_chunks(u16* Ma, u16* Mb, const u16* Kf0b, const u16* Vb,
                          u16* KfPa, u16* KfPb, const float* Q, const int2* ew,
                          const int* ptr, float* invC, const void* hop, const int* flag,
                          float* hid, hipStream_t stream){
  int nchunks = CD / C;
  for (int ch = 0; ch < nchunks; ++ch){
    int c0 = ch * C;
    if (ch == 0){
      k_hop<C,true ,true ,false><<<NN,64,0,stream>>>(nullptr, Kf0b, Vb, nullptr, KfPa, Q, ew, ptr, invC+0*NN, hop, flag, 1, Ma, hid, c0);
      k_hop<C,false,true ,false><<<NN,64,0,stream>>>(Ma, Kf0b, Vb, KfPa, KfPb, Q, ew, ptr, invC+1*NN, hop, flag, 2, Mb, hid, c0);
      k_hop<C,false,true ,false><<<NN,64,0,stream>>>(Mb, Kf0b, Vb, KfPb, KfPa, Q, ew, ptr, invC+2*NN, hop, flag, 3, Ma, hid, c0);
      k_hop<C,false,true ,true ><<<NN,64,0,stream>>>(Ma, Kf0b, Vb, KfPa, nullptr, Q, ew, ptr, invC+3*NN, hop, flag, 4, nullptr, hid, c0);
    } else {
      k_hop<C,true ,false,false><<<NN,64,0,stream>>>(nullptr, Kf0b, Vb, nullptr, nullptr, Q, ew, ptr, invC+0*NN, hop, flag, 1, Ma, hid, c0);
      k_hop<C,false,false,false><<<NN,64,0,stream>>>(Ma, Kf0b, Vb, nullptr, nullptr, Q, ew, ptr, invC+1*NN, hop, flag, 2, Mb, hid, c0);
      k_hop<C,false,false,false><<<NN,64,0,stream>>>(Mb, Kf0b, Vb, nullptr, nullptr, Q, ew, ptr, invC+2*NN, hop, flag, 3, Ma, hid, c0);
      k_hop<C,false,false,true ><<<NN,64,0,stream>>>(Ma, Kf0b, Vb, nullptr, nullptr, Q, ew, ptr, invC+3*NN, hop, flag, 4, nullptr, hid, c0);
    }
  }
}

// ---------------- launch ----------------

extern "C" void kernel_launch(void* const* d_in, const int* in_sizes, int n_in,
                              void* d_out, int out_size, void* d_ws, size_t ws_size,
                              hipStream_t stream){
  const void* feat = d_in[0];
  const void* Win  = d_in[1];
  const void* bin  = d_in[2];
  const void* WQ   = d_in[3];
  const void* bQ   = d_in[4];
  const void* WK   = d_in[5];
  const void* bK   = d_in[6];
  const void* WV   = d_in[7];
  const void* bV   = d_in[8];
  const void* hop  = d_in[9];
  const void* tel  = d_in[10];
  const int* ei    = (const int*)d_in[11];
  const int* rowp  = ei;
  const int* colp  = ei + EE;

  char* w = (char*)d_ws;
  size_t off = 0;
  auto pad = [](size_t x){ return (x + 255) & ~((size_t)255); };
  auto alloc = [&](size_t bytes) -> char* {
    char* p = w + off;
    off += pad(bytes);
    return p;
  };
  float* Q    = (float*)alloc((size_t)NN * HD * 4);
  float* hid  = (float*)alloc((size_t)NN * CD * 4);
  float* invC = (float*)alloc((size_t)4 * NN * 4);
  float* dinv = (float*)alloc((size_t)NN * 4);
  int*   cnt  = (int*)alloc((size_t)NN * 4);
  int*   ptr  = (int*)alloc((size_t)(NN + 1) * 4);
  int*   fill = (int*)alloc((size_t)NN * 4);
  int*   bsum = (int*)alloc(64 * 4);
  int*   boff = (int*)alloc(64 * 4);
  int2*  ew   = (int2*)alloc((size_t)EE * 8);
  float* teleM= (float*)alloc((size_t)HD * CD * 4);
  float* teleK= (float*)alloc((size_t)HD * 4);
  int*   flag = (int*)alloc(256);
  u16*   Kf0b = (u16*)alloc((size_t)NN * HD * 2);
  u16*   KfPa = (u16*)alloc((size_t)NN * HD * 2);
  u16*   KfPb = (u16*)alloc((size_t)NN * HD * 2);
  u16*   Vb   = (u16*)alloc((size_t)NN * CD * 2);

  size_t fixed = off;
  auto fits = [&](int C){ return fixed + 2 * pad((size_t)NN * HD * C * 2) <= ws_size; };
  int C = fits(16) ? 16 : (fits(8) ? 8 : (fits(4) ? 4 : 2));
  size_t mbytes = pad((size_t)NN * HD * C * 2);
  char* mreg = alloc(2 * mbytes);
  u16* Ma = (u16*)mreg;
  u16* Mb = (u16*)(mreg + mbytes);
  float* x = (float*)mreg;  // x (12.8 MB) aliases M region (>=12.8 MB in all tiers); dead before hops

  k_detect<<<1, 256, 0, stream>>>((const u16*)Win, flag);
  k_zero<<<(NN + 255) / 256, 256, 0, stream>>>(cnt, teleM, teleK);
  k_hist<<<(EE + 255) / 256, 256, 0, stream>>>(colp, cnt);
  k_scanA<<<NB, 1024, 0, stream>>>(cnt, fill, bsum);
  k_scanB<<<1, 64, 0, stream>>>(bsum, boff, ptr + NN);
  k_scanC<<<NB, 1024, 0, stream>>>(cnt, fill, boff, ptr, fill, dinv);
  k_scatter<<<(EE + 255) / 256, 256, 0, stream>>>(rowp, colp, dinv, fill, ew);
  k_x<<<(NN + 3) / 4, 256, 0, stream>>>(feat, Win, bin, flag, x);
  k_qkv<<<(NN + 3) / 4, 256, 0, stream>>>(x, WQ, bQ, WK, bK, WV, bV, hop, flag, Q, Kf0b, Vb, hid);
  k_tele<<<256, 256, 0, stream>>>(Kf0b, Vb, teleM, teleK);

  if (C == 16)      launch_chunks<16>(Ma, Mb, Kf0b, Vb, KfPa, KfPb, Q, ew, ptr, invC, hop, flag, hid, stream);
  else if (C == 8)  launch_chunks<8 >(Ma, Mb, Kf0b, Vb, KfPa, KfPb, Q, ew, ptr, invC, hop, flag, hid, stream);
  else if (C == 4)  launch_chunks<4 >(Ma, Mb, Kf0b, Vb, KfPa, KfPb, Q, ew, ptr, invC, hop, flag, hid, stream);
  else              launch_chunks<2 >(Ma, Mb, Kf0b, Vb, KfPa, KfPb, Q, ew, ptr, invC, hop, flag, hid, stream);

  k_final<<<(NN + 7) / 8, 256, 0, stream>>>(hid, Q, teleM, teleK, tel, flag, d_out);
}